// Round 4
// baseline (5562.729 us; speedup 1.0000x reference)
//
#include <hip/hip_runtime.h>
#include <hip/hip_bf16.h>

#define NFEAT 256
#define NHID  128
#define NCLS  10
#define CONV_TIME 30
#define NSLICE 8          // feature slices == XCD count
#define SFEAT  16         // NHID / NSLICE, 64B rows

// ---------------------------------------------------------------- degree histogram
// NOTE: harness stages integer inputs as int32 (NOT int64) — read as int.
__global__ void deg_kernel(const int* __restrict__ ei, int* __restrict__ cnt, int E) {
    int e = blockIdx.x * blockDim.x + threadIdx.x;
    if (e < E) {
        int d = ei[(size_t)E + e];   // edge_index[1][e]
        atomicAdd(&cnt[d], 1);
    }
}

// ---------------------------------------------------------------- dinv = 1/sqrt(deg+1)
__global__ void dinv_kernel(const int* __restrict__ cnt, float* __restrict__ dinv, int n) {
    int i = blockIdx.x * blockDim.x + threadIdx.x;
    if (i < n) {
        float deg = (float)(cnt[i] + 1);   // +1 self loop; always >= 1
        dinv[i] = 1.0f / sqrtf(deg);
    }
}

// ---------------------------------------------------------------- exclusive scan (single block)
__global__ void scan_kernel(const int* __restrict__ cnt, int* __restrict__ offs,
                            int* __restrict__ pos, int n) {
    __shared__ int lds[256];
    int tid = threadIdx.x;
    int per = (n + 255) >> 8;
    int beg = tid * per;
    int end = min(beg + per, n);
    int sum = 0;
    for (int i = beg; i < end; ++i) sum += cnt[i];
    lds[tid] = sum;
    __syncthreads();
    if (tid == 0) {
        int acc = 0;
        for (int i = 0; i < 256; ++i) { int t = lds[i]; lds[i] = acc; acc += t; }
    }
    __syncthreads();
    int run = lds[tid];
    for (int i = beg; i < end; ++i) { offs[i] = run; pos[i] = run; run += cnt[i]; }
    if (tid == 255) offs[n] = run;
}

// ---------------------------------------------------------------- scatter edges into CSR (by dst)
// Payload is ONLY the src id (4B) — the normalization is folded algebraically
// into the hop recurrence (g = D^{-1/2} h), halving scattered write traffic.
__global__ void scatter_kernel(const int* __restrict__ ei, int* __restrict__ pos,
                               int* __restrict__ esrc, int E) {
    int e = blockIdx.x * blockDim.x + threadIdx.x;
    if (e < E) {
        int s = ei[e];
        int d = ei[(size_t)E + e];
        int p = atomicAdd(&pos[d], 1);
        esrc[p] = s;
    }
}

// ---------------------------------------------------------------- g0 = dinv * (x @ W1 + b1), sliced layout
__global__ __launch_bounds__(256) void gemm1_kernel(const float* __restrict__ x,
                                                    const float* __restrict__ W1,
                                                    const float* __restrict__ b1,
                                                    const float* __restrict__ dinv,
                                                    float* __restrict__ g, int M) {
    __shared__ float As[64][20];
    __shared__ float Bs[16][128];
    int tid = threadIdx.x;
    int m0  = blockIdx.x * 64;
    int tx  = tid & 15;
    int ty  = tid >> 4;
    int ar  = tid >> 2, aq = tid & 3;
    int br  = tid >> 4, bc = tid & 15;

    float acc[4][8];
#pragma unroll
    for (int i = 0; i < 4; ++i)
#pragma unroll
        for (int j = 0; j < 8; ++j) acc[i][j] = 0.0f;

    for (int kb = 0; kb < NFEAT; kb += 16) {
        float4 av = make_float4(0.f, 0.f, 0.f, 0.f);
        int arow = m0 + ar;
        if (arow < M) av = *(const float4*)(x + (size_t)arow * NFEAT + kb + aq * 4);
        *(float4*)&As[ar][aq * 4] = av;
        *(float4*)&Bs[br][bc * 8]     = *(const float4*)(W1 + (size_t)(kb + br) * NHID + bc * 8);
        *(float4*)&Bs[br][bc * 8 + 4] = *(const float4*)(W1 + (size_t)(kb + br) * NHID + bc * 8 + 4);
        __syncthreads();
#pragma unroll
        for (int k = 0; k < 16; ++k) {
            float a0 = As[ty * 4 + 0][k];
            float a1 = As[ty * 4 + 1][k];
            float a2 = As[ty * 4 + 2][k];
            float a3 = As[ty * 4 + 3][k];
            float4 b0 = *(float4*)&Bs[k][tx * 8];
            float4 b1v = *(float4*)&Bs[k][tx * 8 + 4];
            float bv[8] = {b0.x, b0.y, b0.z, b0.w, b1v.x, b1v.y, b1v.z, b1v.w};
            float avv[4] = {a0, a1, a2, a3};
#pragma unroll
            for (int i = 0; i < 4; ++i)
#pragma unroll
                for (int j = 0; j < 8; ++j)
                    acc[i][j] = fmaf(avv[i], bv[j], acc[i][j]);
        }
        __syncthreads();
    }
    int col0 = tx * 8;
    int sl   = col0 >> 4;          // feature slice
    int c0   = col0 & 15;
#pragma unroll
    for (int i = 0; i < 4; ++i) {
        int row = m0 + ty * 4 + i;
        if (row < M) {
            float dv = dinv[row];
            float* dst = g + (size_t)sl * M * SFEAT + (size_t)row * SFEAT + c0;
#pragma unroll
            for (int j = 0; j < 8; ++j)
                dst[j] = dv * (acc[i][j] + b1[col0 + j]);
        }
    }
}

// ---------------------------------------------------------------- one propagation hop (sliced)
// blockIdx & 7 selects the feature slice (maps round-robin onto the 8 XCDs so
// each XCD's gathers stay inside its own 3.2MB slice -> L2-resident).
// One wave per node: 64 lanes = 4 edge-slots x 16 feats; one gather instruction
// covers 4 edges; esrc broadcast by one ds_bpermute per 4 edges.
// Recurrence: g' = scale * (sum_{s in N(d)} g[s] + g[d]),
//   scale = dv*dv (inner hops, keeps g = D^{-1/2} h) or dv (last hop -> emits h).
__global__ __launch_bounds__(256) void hop_kernel(const float* __restrict__ gin,
                                                  float* __restrict__ gout,
                                                  const int* __restrict__ offs,
                                                  const int* __restrict__ esrc,
                                                  const float* __restrict__ dinv,
                                                  int n, int last) {
    int bid  = blockIdx.x;
    int sl   = bid & (NSLICE - 1);
    int node = (bid >> 3) * 4 + (threadIdx.x >> 6);
    if (node >= n) return;
    int lane = threadIdx.x & 63;
    int feat = lane & (SFEAT - 1);
    int slot = lane >> 4;                       // 0..3
    const float* __restrict__ gs = gin  + (size_t)sl * n * SFEAT;
    float*       __restrict__ go = gout + (size_t)sl * n * SFEAT;
    int beg = offs[node];
    int end = offs[node + 1];
    float dv   = dinv[node];
    float self = gs[(size_t)node * SFEAT + feat];
    float acc = 0.0f;

    for (int e0 = beg; e0 < end; e0 += 64) {
        int cs = end - e0; if (cs > 64) cs = 64;
        int sv = 0;
        if (lane < cs) sv = esrc[e0 + lane];
#pragma unroll 4
        for (int i = 0; i < cs; i += 4) {
            int idx = i + slot;                 // i<=60, slot<=3 -> idx<=63 always
            int s_  = __shfl(sv, idx, 64);
            float v = gs[(size_t)s_ * SFEAT + feat];
            if (idx < cs) acc += v;
        }
    }
    acc += __shfl_xor(acc, 16, 64);
    acc += __shfl_xor(acc, 32, 64);
    acc += self;
    float r = last ? (dv * acc) : (dv * dv * acc);
    if (slot == 0) go[(size_t)node * SFEAT + feat] = r;
}

// ---------------------------------------------------------------- out = relu(h) @ Wc + bc (sliced h)
__global__ __launch_bounds__(256) void cls_kernel(const float* __restrict__ h,
                                                  const float* __restrict__ Wc,
                                                  const float* __restrict__ bc,
                                                  float* __restrict__ out, int n) {
    __shared__ float wc[NHID * NCLS];
    __shared__ float bcs[NCLS];
    int tid = threadIdx.x;
    for (int i = tid; i < NHID * NCLS; i += 256) wc[i] = Wc[i];
    if (tid < NCLS) bcs[tid] = bc[tid];
    __syncthreads();
    int i = blockIdx.x * 256 + tid;
    if (i >= n) return;
    float acc[NCLS];
#pragma unroll
    for (int c = 0; c < NCLS; ++c) acc[c] = bcs[c];
#pragma unroll
    for (int s = 0; s < NSLICE; ++s) {
        const float4* hr = (const float4*)(h + ((size_t)s * n + i) * SFEAT);
#pragma unroll
        for (int q = 0; q < 4; ++q) {
            float4 v = hr[q];
            float vs[4] = {fmaxf(v.x, 0.f), fmaxf(v.y, 0.f), fmaxf(v.z, 0.f), fmaxf(v.w, 0.f)};
#pragma unroll
            for (int j = 0; j < 4; ++j)
#pragma unroll
                for (int c = 0; c < NCLS; ++c)
                    acc[c] = fmaf(vs[j], wc[(s * SFEAT + q * 4 + j) * NCLS + c], acc[c]);
        }
    }
#pragma unroll
    for (int c = 0; c < NCLS; ++c) out[(size_t)i * NCLS + c] = acc[c];
}

// ----------------------------------------------------------------
static inline size_t align256(size_t x) { return (x + 255) & ~(size_t)255; }

extern "C" void kernel_launch(void* const* d_in, const int* in_sizes, int n_in,
                              void* d_out, int out_size, void* d_ws, size_t ws_size,
                              hipStream_t stream) {
    const float* x   = (const float*)d_in[0];
    const int*   ei  = (const int*)d_in[1];     // int64 in reference -> staged as int32
    const float* W1  = (const float*)d_in[2];
    const float* b1  = (const float*)d_in[3];
    const float* Wc  = (const float*)d_in[4];
    const float* bc  = (const float*)d_in[5];
    float*       out = (float*)d_out;

    const int N = in_sizes[0] / NFEAT;     // 50000
    const int E = in_sizes[1] / 2;         // 1600000

    char* ws = (char*)d_ws;
    size_t off = 0;
    float* hA    = (float*)(ws + off); off = align256(off + (size_t)N * NHID * 4);
    float* hB    = (float*)(ws + off); off = align256(off + (size_t)N * NHID * 4);
    int*   cnt   = (int*)  (ws + off); off = align256(off + (size_t)N * 4);
    float* dinv  = (float*)(ws + off); off = align256(off + (size_t)(N + 1) * 4);
    int*   offs  = (int*)  (ws + off); off = align256(off + (size_t)(N + 1) * 4);
    int*   pos   = (int*)  (ws + off); off = align256(off + (size_t)N * 4);
    int*   esrc  = (int*)  (ws + off); off = align256(off + (size_t)E * 4);

    hipMemsetAsync(cnt, 0, (size_t)N * 4, stream);

    deg_kernel<<<(E + 255) / 256, 256, 0, stream>>>(ei, cnt, E);
    dinv_kernel<<<(N + 255) / 256, 256, 0, stream>>>(cnt, dinv, N);
    scan_kernel<<<1, 256, 0, stream>>>(cnt, offs, pos, N);
    scatter_kernel<<<(E + 255) / 256, 256, 0, stream>>>(ei, pos, esrc, E);

    gemm1_kernel<<<(N + 63) / 64, 256, 0, stream>>>(x, W1, b1, dinv, hA, N);

    int hop_blocks = NSLICE * ((N + 3) / 4);
    for (int i = 0; i < CONV_TIME; ++i) {
        const float* gi = (i & 1) ? hB : hA;
        float*       go = (i & 1) ? hA : hB;
        hop_kernel<<<hop_blocks, 256, 0, stream>>>(gi, go, offs, esrc, dinv, N,
                                                   (i == CONV_TIME - 1) ? 1 : 0);
    }

    cls_kernel<<<(N + 255) / 256, 256, 0, stream>>>(hA, Wc, bc, out, N);
}